// Round 1
// baseline (218.188 us; speedup 1.0000x reference)
//
#include <hip/hip_runtime.h>
#include <math.h>

#define HH 512
#define WW 512
#define NB 8
#define ROWS_PER_BLOCK 8
#define NACC 72   // 45 sym AtA + 27 Atb

// ---------------------------------------------------------------------------
// Kernel 1: per-pixel SH basis + normal-equation accumulation.
// Grid: (HH/ROWS_PER_BLOCK, NB) blocks of 256 threads.
// Each thread: register-accumulate 72 partial sums over its pixels, then
// wave shuffle-reduce -> LDS cross-wave reduce -> one atomicAdd per value.
// ---------------------------------------------------------------------------
__global__ void accum_kernel(const float* __restrict__ img,   // (B,3,H,W)
                             const float* __restrict__ dep,   // (B,1,H,W)
                             const float* __restrict__ alb,   // (B,3,H,W)
                             float* __restrict__ ws)          // (B,72), pre-zeroed
{
    const int b   = blockIdx.y;
    const int y0  = blockIdx.x * ROWS_PER_BLOCK;
    const int tid = threadIdx.x;

    // SH constants (double math, constant-folded at compile time; PI=3.14159
    // exactly as the reference uses)
    const float c0 = (float)(3.14159 * sqrt(1.0 / (4.0 * 3.14159)));
    const float c1 = (float)(2.0 * 3.14159 / 3.0 * sqrt(3.0 / (4.0 * 3.14159)));
    const float c2 = (float)(3.14159 / 4.0 * 0.5 * sqrt(5.0 / (4.0 * 3.14159)));
    const float c3 = (float)(3.14159 / 4.0 * 3.0 * sqrt(5.0 / (12.0 * 3.14159)));
    const float c4 = (float)(3.14159 / 4.0 * 3.0 * sqrt(5.0 / (48.0 * 3.14159)));

    float acc[NACC];
#pragma unroll
    for (int i = 0; i < NACC; ++i) acc[i] = 0.0f;

    const float* depb  = dep + (size_t)b * HH * WW;
    const float* img0b = img + (size_t)(b * 3 + 0) * HH * WW;
    const float* img1b = img + (size_t)(b * 3 + 1) * HH * WW;
    const float* img2b = img + (size_t)(b * 3 + 2) * HH * WW;
    const float* alb2b = alb + (size_t)(b * 3 + 2) * HH * WW;

    for (int r = 0; r < ROWS_PER_BLOCK; ++r) {
        const int y = y0 + r;
        if (y < 1 || y >= HH - 1) continue;   // padded boundary -> zero contribution
        const float fy  = ((float)y       - 256.0f) / 608.365f;
        const float fyd = ((float)(y + 1) - 256.0f) / 608.365f;
        const float fyu = ((float)(y - 1) - 256.0f) / 608.365f;
        for (int xi = 0; xi < 2; ++xi) {
            const int x = 1 + tid + xi * 256;
            if (x >= WW - 1) continue;
            const int idx = y * WW + x;

            // depth stencil: depth = (d+1)/2
            const float dc = (depb[idx]      + 1.0f) * 0.5f;
            const float dr = (depb[idx + 1]  + 1.0f) * 0.5f;
            const float dl = (depb[idx - 1]  + 1.0f) * 0.5f;
            const float dd = (depb[idx + WW] + 1.0f) * 0.5f;
            const float du = (depb[idx - WW] + 1.0f) * 0.5f;

            const float fx  = ((float)x       - 256.0f) / 608.365f;
            const float fxr = ((float)(x + 1) - 256.0f) / 608.365f;
            const float fxl = ((float)(x - 1) - 256.0f) / 608.365f;

            // 3D points
            const float pcx = fx  * dc, pcy = fy  * dc;
            const float prx = fxr * dr, pry = fy  * dr;
            const float plx = fxl * dl, ply = fy  * dl;
            const float pdx = fx  * dd, pdy = fyd * dd;
            const float pux = fx  * du, puy = fyu * du;

            // vw = pc-pr ; vs = pd-pc ; ve = pc-pl ; vn = pu-pc
            const float vwx = pcx - prx, vwy = pcy - pry, vwz = dc - dr;
            const float vsx = pdx - pcx, vsy = pdy - pcy, vsz = dd - dc;
            const float vex = pcx - plx, vey = pcy - ply, vez = dc - dl;
            const float vnx = pux - pcx, vny = puy - pcy, vnz = du - dc;

            // normal = cross(vw,vs) + cross(ve,vn)
            const float nx = (vwy * vsz - vwz * vsy) + (vey * vnz - vez * vny);
            const float ny = (vwz * vsx - vwx * vsz) + (vez * vnx - vex * vnz);
            const float nz = (vwx * vsy - vwy * vsx) + (vex * vny - vey * vnx);

            const float nn   = nx * nx + ny * ny + nz * nz;
            const float mag  = sqrtf(nn);
            const float invm = 1.0f / mag;
            const float uxn = nx * invm, uyn = ny * invm, uzn = nz * invm;
            const float x2 = uxn * uxn, y2 = uyn * uyn, z2 = uzn * uzn;

            const float N0 = c0 * mag;
            const float N1 = c1 * nz;
            const float N2 = c1 * nx;
            const float N3 = c1 * ny;
            const float N4 = c2 * (2.0f * z2 - x2 - y2) * mag;
            const float N5 = c3 * (uxn * uzn) * mag;
            const float N6 = c3 * (uyn * uzn) * mag;
            const float N7 = c4 * (x2 - y2) * mag;
            const float N8 = c3 * (uxn * uyn) * mag;

            // mask from img channel 0 (img = (in+1)/2, mask = img0 != 0)
            const float i0 = (img0b[idx] + 1.0f) * 0.5f;
            const float i1 = (img1b[idx] + 1.0f) * 0.5f;
            const float i2 = (img2b[idx] + 1.0f) * 0.5f;
            const float m  = (i0 != 0.0f) ? 1.0f : 0.0f;
            const float b0 = i0 * m, b1 = i1 * m, b2 = i2 * m;
            const float rho = alb2b[idx] * m;

            float A[9] = {N0 * rho, N1 * rho, N2 * rho, N3 * rho, N4 * rho,
                          N5 * rho, N6 * rho, N7 * rho, N8 * rho};

            int k = 0;
#pragma unroll
            for (int i = 0; i < 9; ++i) {
#pragma unroll
                for (int j = i; j < 9; ++j) {
                    acc[k] = fmaf(A[i], A[j], acc[k]);
                    ++k;
                }
            }
#pragma unroll
            for (int i = 0; i < 9; ++i) {
                acc[45 + i] = fmaf(b0, A[i], acc[45 + i]);
                acc[54 + i] = fmaf(b1, A[i], acc[54 + i]);
                acc[63 + i] = fmaf(b2, A[i], acc[63 + i]);
            }
        }
    }

    // wave (64-lane) butterfly reduce each of the 72 values
#pragma unroll
    for (int i = 0; i < NACC; ++i) {
        float v = acc[i];
        v += __shfl_xor(v, 32, 64);
        v += __shfl_xor(v, 16, 64);
        v += __shfl_xor(v, 8, 64);
        v += __shfl_xor(v, 4, 64);
        v += __shfl_xor(v, 2, 64);
        v += __shfl_xor(v, 1, 64);
        acc[i] = v;
    }

    __shared__ float red[4][NACC];
    const int wave = tid >> 6;
    const int lane = tid & 63;
    if (lane == 0) {
#pragma unroll
        for (int i = 0; i < NACC; ++i) red[wave][i] = acc[i];
    }
    __syncthreads();
    if (tid < NACC) {
        const float s = red[0][tid] + red[1][tid] + red[2][tid] + red[3][tid];
        atomicAdd(&ws[b * NACC + tid], s);
    }
}

// ---------------------------------------------------------------------------
// Kernel 2: per-batch 9x9 solve with 3 RHS (partial-pivot Gaussian elim).
// One thread per batch; matrices live in LDS. Output S is (B,3,9).
// ---------------------------------------------------------------------------
__global__ void solve_kernel(const float* __restrict__ ws, float* __restrict__ out)
{
    __shared__ float M[NB][9][12];
    const int b = threadIdx.x;
    if (b >= NB) return;

    const float* w = ws + b * NACC;
    int k = 0;
    for (int i = 0; i < 9; ++i) {
        for (int j = i; j < 9; ++j) {
            M[b][i][j] = w[k];
            M[b][j][i] = w[k];
            ++k;
        }
    }
    for (int c = 0; c < 3; ++c)
        for (int i = 0; i < 9; ++i)
            M[b][i][9 + c] = w[45 + c * 9 + i];

    // forward elimination with partial pivoting
    for (int kk = 0; kk < 9; ++kk) {
        int piv = kk;
        float best = fabsf(M[b][kk][kk]);
        for (int i = kk + 1; i < 9; ++i) {
            const float v = fabsf(M[b][i][kk]);
            if (v > best) { best = v; piv = i; }
        }
        if (piv != kk) {
            for (int j = 0; j < 12; ++j) {
                const float t = M[b][kk][j];
                M[b][kk][j] = M[b][piv][j];
                M[b][piv][j] = t;
            }
        }
        const float inv = 1.0f / M[b][kk][kk];
        for (int i = kk + 1; i < 9; ++i) {
            const float f = M[b][i][kk] * inv;
            for (int j = kk; j < 12; ++j)
                M[b][i][j] -= f * M[b][kk][j];
        }
    }
    // back substitution
    for (int c = 0; c < 3; ++c) {
        float sol[9];
        for (int kk = 8; kk >= 0; --kk) {
            float v = M[b][kk][9 + c];
            for (int j = kk + 1; j < 9; ++j) v -= M[b][kk][j] * sol[j];
            sol[kk] = v / M[b][kk][kk];
        }
        for (int kk = 0; kk < 9; ++kk)
            out[(b * 3 + c) * 9 + kk] = sol[kk];
    }
}

extern "C" void kernel_launch(void* const* d_in, const int* in_sizes, int n_in,
                              void* d_out, int out_size, void* d_ws, size_t ws_size,
                              hipStream_t stream) {
    const float* img = (const float*)d_in[0];   // input_img  (8,3,512,512)
    const float* dep = (const float*)d_in[1];   // depth_target (8,1,512,512)
    const float* alb = (const float*)d_in[2];   // albedo (8,3,512,512)
    float* out = (float*)d_out;                 // S (8,3,9)
    float* ws  = (float*)d_ws;                  // 8*72 floats of accumulators

    hipMemsetAsync(ws, 0, NB * NACC * sizeof(float), stream);

    dim3 grid(HH / ROWS_PER_BLOCK, NB);
    accum_kernel<<<grid, 256, 0, stream>>>(img, dep, alb, ws);
    solve_kernel<<<1, 64, 0, stream>>>(ws, out);
}

// Round 2
// 112.046 us; speedup vs baseline: 1.9473x; 1.9473x over previous
//
#include <hip/hip_runtime.h>
#include <math.h>

#define HH 512
#define WW 512
#define NB 8
#define ROWS_PER_BLOCK 8
#define NACC 72   // 45 sym AtA + 27 Atb

// ---------------------------------------------------------------------------
// Kernel 1: per-pixel SH basis + normal-equation accumulation.
// Grid: (HH/ROWS_PER_BLOCK, NB) blocks of 256 threads.
// __launch_bounds__(256, 2): 72 accumulators + temps need ~130 VGPRs; the
// default allocator capped at 64 and spilled acc[] to scratch (R1 counters:
// WRITE_SIZE 249 MB, VALUBusy 11%). 2 waves/EU -> up to 256 VGPRs, no spill.
// ---------------------------------------------------------------------------
__global__ __launch_bounds__(256, 2)
void accum_kernel(const float* __restrict__ img,   // (B,3,H,W)
                  const float* __restrict__ dep,   // (B,1,H,W)
                  const float* __restrict__ alb,   // (B,3,H,W)
                  float* __restrict__ ws)          // (B,72), pre-zeroed
{
    const int b   = blockIdx.y;
    const int y0  = blockIdx.x * ROWS_PER_BLOCK;
    const int tid = threadIdx.x;

    // SH constants (double math, constant-folded at compile time; PI=3.14159
    // exactly as the reference uses)
    const float c0 = (float)(3.14159 * sqrt(1.0 / (4.0 * 3.14159)));
    const float c1 = (float)(2.0 * 3.14159 / 3.0 * sqrt(3.0 / (4.0 * 3.14159)));
    const float c2 = (float)(3.14159 / 4.0 * 0.5 * sqrt(5.0 / (4.0 * 3.14159)));
    const float c3 = (float)(3.14159 / 4.0 * 3.0 * sqrt(5.0 / (12.0 * 3.14159)));
    const float c4 = (float)(3.14159 / 4.0 * 3.0 * sqrt(5.0 / (48.0 * 3.14159)));

    float acc[NACC];
#pragma unroll
    for (int i = 0; i < NACC; ++i) acc[i] = 0.0f;

    const float* depb  = dep + (size_t)b * HH * WW;
    const float* img0b = img + (size_t)(b * 3 + 0) * HH * WW;
    const float* img1b = img + (size_t)(b * 3 + 1) * HH * WW;
    const float* img2b = img + (size_t)(b * 3 + 2) * HH * WW;
    const float* alb2b = alb + (size_t)(b * 3 + 2) * HH * WW;

    for (int r = 0; r < ROWS_PER_BLOCK; ++r) {
        const int y = y0 + r;
        if (y < 1 || y >= HH - 1) continue;   // padded boundary -> zero contribution
        const float fy  = ((float)y       - 256.0f) / 608.365f;
        const float fyd = ((float)(y + 1) - 256.0f) / 608.365f;
        const float fyu = ((float)(y - 1) - 256.0f) / 608.365f;
        for (int xi = 0; xi < 2; ++xi) {
            const int x = 1 + tid + xi * 256;
            if (x >= WW - 1) continue;
            const int idx = y * WW + x;

            // depth stencil: depth = (d+1)/2
            const float dc = (depb[idx]      + 1.0f) * 0.5f;
            const float dr = (depb[idx + 1]  + 1.0f) * 0.5f;
            const float dl = (depb[idx - 1]  + 1.0f) * 0.5f;
            const float dd = (depb[idx + WW] + 1.0f) * 0.5f;
            const float du = (depb[idx - WW] + 1.0f) * 0.5f;

            const float fx  = ((float)x       - 256.0f) / 608.365f;
            const float fxr = ((float)(x + 1) - 256.0f) / 608.365f;
            const float fxl = ((float)(x - 1) - 256.0f) / 608.365f;

            // 3D points
            const float pcx = fx  * dc, pcy = fy  * dc;
            const float prx = fxr * dr, pry = fy  * dr;
            const float plx = fxl * dl, ply = fy  * dl;
            const float pdx = fx  * dd, pdy = fyd * dd;
            const float pux = fx  * du, puy = fyu * du;

            // vw = pc-pr ; vs = pd-pc ; ve = pc-pl ; vn = pu-pc
            const float vwx = pcx - prx, vwy = pcy - pry, vwz = dc - dr;
            const float vsx = pdx - pcx, vsy = pdy - pcy, vsz = dd - dc;
            const float vex = pcx - plx, vey = pcy - ply, vez = dc - dl;
            const float vnx = pux - pcx, vny = puy - pcy, vnz = du - dc;

            // normal = cross(vw,vs) + cross(ve,vn)
            const float nx = (vwy * vsz - vwz * vsy) + (vey * vnz - vez * vny);
            const float ny = (vwz * vsx - vwx * vsz) + (vez * vnx - vex * vnz);
            const float nz = (vwx * vsy - vwy * vsx) + (vex * vny - vey * vnx);

            const float nn   = nx * nx + ny * ny + nz * nz;
            const float mag  = sqrtf(nn);
            const float invm = 1.0f / mag;
            const float uxn = nx * invm, uyn = ny * invm, uzn = nz * invm;
            const float x2 = uxn * uxn, y2 = uyn * uyn, z2 = uzn * uzn;

            const float N0 = c0 * mag;
            const float N1 = c1 * nz;
            const float N2 = c1 * nx;
            const float N3 = c1 * ny;
            const float N4 = c2 * (2.0f * z2 - x2 - y2) * mag;
            const float N5 = c3 * (uxn * uzn) * mag;
            const float N6 = c3 * (uyn * uzn) * mag;
            const float N7 = c4 * (x2 - y2) * mag;
            const float N8 = c3 * (uxn * uyn) * mag;

            // mask from img channel 0 (img = (in+1)/2, mask = img0 != 0)
            const float i0 = (img0b[idx] + 1.0f) * 0.5f;
            const float i1 = (img1b[idx] + 1.0f) * 0.5f;
            const float i2 = (img2b[idx] + 1.0f) * 0.5f;
            const float m  = (i0 != 0.0f) ? 1.0f : 0.0f;
            const float b0 = i0 * m, b1 = i1 * m, b2 = i2 * m;
            const float rho = alb2b[idx] * m;

            float A[9] = {N0 * rho, N1 * rho, N2 * rho, N3 * rho, N4 * rho,
                          N5 * rho, N6 * rho, N7 * rho, N8 * rho};

            int k = 0;
#pragma unroll
            for (int i = 0; i < 9; ++i) {
#pragma unroll
                for (int j = i; j < 9; ++j) {
                    acc[k] = fmaf(A[i], A[j], acc[k]);
                    ++k;
                }
            }
#pragma unroll
            for (int i = 0; i < 9; ++i) {
                acc[45 + i] = fmaf(b0, A[i], acc[45 + i]);
                acc[54 + i] = fmaf(b1, A[i], acc[54 + i]);
                acc[63 + i] = fmaf(b2, A[i], acc[63 + i]);
            }
        }
    }

    // wave (64-lane) butterfly reduce each of the 72 values
#pragma unroll
    for (int i = 0; i < NACC; ++i) {
        float v = acc[i];
        v += __shfl_xor(v, 32, 64);
        v += __shfl_xor(v, 16, 64);
        v += __shfl_xor(v, 8, 64);
        v += __shfl_xor(v, 4, 64);
        v += __shfl_xor(v, 2, 64);
        v += __shfl_xor(v, 1, 64);
        acc[i] = v;
    }

    __shared__ float red[4][NACC];
    const int wave = tid >> 6;
    const int lane = tid & 63;
    if (lane == 0) {
#pragma unroll
        for (int i = 0; i < NACC; ++i) red[wave][i] = acc[i];
    }
    __syncthreads();
    if (tid < NACC) {
        const float s = red[0][tid] + red[1][tid] + red[2][tid] + red[3][tid];
        atomicAdd(&ws[b * NACC + tid], s);
    }
}

// ---------------------------------------------------------------------------
// Kernel 2: per-batch 9x9 solve with 3 RHS (partial-pivot Gaussian elim).
// One thread per batch; matrices live in LDS. Output S is (B,3,9).
// ---------------------------------------------------------------------------
__global__ void solve_kernel(const float* __restrict__ ws, float* __restrict__ out)
{
    __shared__ float M[NB][9][12];
    const int b = threadIdx.x;
    if (b >= NB) return;

    const float* w = ws + b * NACC;
    int k = 0;
    for (int i = 0; i < 9; ++i) {
        for (int j = i; j < 9; ++j) {
            M[b][i][j] = w[k];
            M[b][j][i] = w[k];
            ++k;
        }
    }
    for (int c = 0; c < 3; ++c)
        for (int i = 0; i < 9; ++i)
            M[b][i][9 + c] = w[45 + c * 9 + i];

    // forward elimination with partial pivoting
    for (int kk = 0; kk < 9; ++kk) {
        int piv = kk;
        float best = fabsf(M[b][kk][kk]);
        for (int i = kk + 1; i < 9; ++i) {
            const float v = fabsf(M[b][i][kk]);
            if (v > best) { best = v; piv = i; }
        }
        if (piv != kk) {
            for (int j = 0; j < 12; ++j) {
                const float t = M[b][kk][j];
                M[b][kk][j] = M[b][piv][j];
                M[b][piv][j] = t;
            }
        }
        const float inv = 1.0f / M[b][kk][kk];
        for (int i = kk + 1; i < 9; ++i) {
            const float f = M[b][i][kk] * inv;
            for (int j = kk; j < 12; ++j)
                M[b][i][j] -= f * M[b][kk][j];
        }
    }
    // back substitution
    for (int c = 0; c < 3; ++c) {
        float sol[9];
        for (int kk = 8; kk >= 0; --kk) {
            float v = M[b][kk][9 + c];
            for (int j = kk + 1; j < 9; ++j) v -= M[b][kk][j] * sol[j];
            sol[kk] = v / M[b][kk][kk];
        }
        for (int kk = 0; kk < 9; ++kk)
            out[(b * 3 + c) * 9 + kk] = sol[kk];
    }
}

extern "C" void kernel_launch(void* const* d_in, const int* in_sizes, int n_in,
                              void* d_out, int out_size, void* d_ws, size_t ws_size,
                              hipStream_t stream) {
    const float* img = (const float*)d_in[0];   // input_img  (8,3,512,512)
    const float* dep = (const float*)d_in[1];   // depth_target (8,1,512,512)
    const float* alb = (const float*)d_in[2];   // albedo (8,3,512,512)
    float* out = (float*)d_out;                 // S (8,3,9)
    float* ws  = (float*)d_ws;                  // 8*72 floats of accumulators

    hipMemsetAsync(ws, 0, NB * NACC * sizeof(float), stream);

    dim3 grid(HH / ROWS_PER_BLOCK, NB);
    accum_kernel<<<grid, 256, 0, stream>>>(img, dep, alb, ws);
    solve_kernel<<<1, 64, 0, stream>>>(ws, out);
}